// Round 10
// baseline (495.613 us; speedup 1.0000x reference)
//
#include <hip/hip_runtime.h>
#include <hip/hip_bf16.h>

#define CHS 13   // src-chunk shift: 8192 rows = 2 MB of P/hs per chunk (fits 4 MB per-XCD L2)

// ---------------- chunked degree: degc[(s>>CHS)*N + d] ----------------
__global__ __launch_bounds__(256) void k_deg(const int* __restrict__ src, const int* __restrict__ dst,
                                             int* __restrict__ degc, int E, int N) {
    int e = blockIdx.x * 256 + threadIdx.x;
    if (e < E) {
        int s = src[e], d = dst[e];
        atomicAdd(&degc[(s >> CHS) * N + d], 1);
    }
}

// dinv[n] = rsqrt(total_deg(n) + 1); total over NCH chunk counters
__global__ __launch_bounds__(256) void k_dinv(const int* __restrict__ degc, float* __restrict__ dinv,
                                              int N, int NCH) {
    int n = blockIdx.x * 256 + threadIdx.x;
    if (n < N) {
        int v = 0;
        for (int c = 0; c < NCH; ++c) v += degc[c * N + n];
        dinv[n] = rsqrtf((float)(v + 1));
    }
}

// ---------------- exclusive scan over T = NCH*N entries ----------------
__global__ __launch_bounds__(256) void k_scan_sum(const int* __restrict__ deg, int* __restrict__ bsum, int T) {
    int n = blockIdx.x * 256 + threadIdx.x;
    int v = (n < T) ? deg[n] : 0;
#pragma unroll
    for (int o = 32; o > 0; o >>= 1) v += __shfl_down(v, o, 64);
    __shared__ int sh[4];
    if ((threadIdx.x & 63) == 0) sh[threadIdx.x >> 6] = v;
    __syncthreads();
    if (threadIdx.x == 0) bsum[blockIdx.x] = sh[0] + sh[1] + sh[2] + sh[3];
}

// multi-tile in-place exclusive scan of bsum[0..nb), single block, serial tiles with carry
__global__ __launch_bounds__(256) void k_scan_off(int* __restrict__ bsum, int nb) {
    __shared__ int sh[256];
    __shared__ int carry_s;
    int t = threadIdx.x;
    if (t == 0) carry_s = 0;
    __syncthreads();
    for (int base = 0; base < nb; base += 256) {
        int idx = base + t;
        int v = (idx < nb) ? bsum[idx] : 0;
        sh[t] = v;
        __syncthreads();
        for (int o = 1; o < 256; o <<= 1) {
            int y = (t >= o) ? sh[t - o] : 0;
            __syncthreads();
            sh[t] += y;
            __syncthreads();
        }
        int incl = sh[t];
        int carry = carry_s;
        if (idx < nb) bsum[idx] = carry + incl - v;   // exclusive
        __syncthreads();
        if (t == 255) carry_s = carry + incl;         // incl@255 = tile total
        __syncthreads();
    }
}

__global__ __launch_bounds__(256) void k_scan_write(const int* __restrict__ deg, const int* __restrict__ boff,
                                                    int* __restrict__ row_start, int* __restrict__ cursor, int T) {
    int n = blockIdx.x * 256 + threadIdx.x;
    int t = threadIdx.x, lane = t & 63, w = t >> 6;
    int v = (n < T) ? deg[n] : 0;
    int x = v;
#pragma unroll
    for (int o = 1; o < 64; o <<= 1) {
        int y = __shfl_up(x, o, 64);
        if (lane >= o) x += y;
    }
    __shared__ int wsum[4];
    if (lane == 63) wsum[w] = x;
    __syncthreads();
    int wo = 0;
#pragma unroll
    for (int i = 0; i < 4; ++i) wo += (i < w) ? wsum[i] : 0;
    int excl = boff[blockIdx.x] + wo + x - v;
    if (n < T) { row_start[n] = excl; cursor[n] = excl; }
    if (n == T - 1) row_start[T] = excl + v;
}

// fill in (chunk(s), d) order. PAIR: item[pos] = {s, e}; else item[pos] = e
template <bool PAIR>
__global__ __launch_bounds__(256) void k_fill(const int* __restrict__ src, const int* __restrict__ dst,
                                              int* __restrict__ cursor, void* __restrict__ item, int E, int N) {
    int e = blockIdx.x * 256 + threadIdx.x;
    if (e < E) {
        int s = src[e], d = dst[e];
        int pos = atomicAdd(&cursor[(s >> CHS) * N + d], 1);
        if (PAIR) ((int2*)item)[pos] = make_int2(s, e);
        else      ((int*)item)[pos] = e;
    }
}

// ---------------- dvec[i] = d for flattened-CSR position i (thread per (c,d) row) ----------------
__global__ __launch_bounds__(256) void k_dvec(const int* __restrict__ rowst, int* __restrict__ dvec,
                                              int N, int T) {
    int f = blockIdx.x * 256 + threadIdx.x;
    if (f >= T) return;
    int beg = rowst[f], end = rowst[f + 1];
    int d = f % N;   // f = c*N + d
    for (int k = beg; k < end; ++k) dvec[k] = d;
}

// ---------------- merged weight prep: W1T, W2T, Wm2T, WPQ in one dispatch ----------------
__global__ __launch_bounds__(256) void k_prep(const float* __restrict__ W1, const float* __restrict__ W2,
                                              const float* __restrict__ Wm2, const float* __restrict__ Wm1,
                                              float* __restrict__ W1T, float* __restrict__ W2T,
                                              float* __restrict__ Wm2T, float* __restrict__ WPQ,
                                              int IN, int H) {
    int i = blockIdx.x * 256 + threadIdx.x;
    int n1 = IN * H, n2 = H * H, n3 = H * 16, n4 = 2 * H * H;
    if (i < n1) {
        int r = i / H, c = i % H;
        W1T[(size_t)c * IN + r] = W1[(size_t)r * H + c];
    } else if ((i -= n1) < n2) {
        int r = i / H, c = i % H;
        W2T[(size_t)c * H + r] = W2[(size_t)r * H + c];
    } else if ((i -= n2) < n3) {
        int r = i / 16, c = i % 16;
        Wm2T[(size_t)c * H + r] = Wm2[(size_t)r * 16 + c];
    } else if ((i -= n3) < n4) {
        int j = i >> 6, k = i & 63;   // H == 64
        WPQ[i] = (j < 64) ? Wm1[k * 64 + j] : Wm1[(64 + k) * 64 + (j - 64)];
    }
}

// ---------------- column-sliced node GEMM (HW-proven round 2) ----------------
// SCALE: write acc*dinv[n]  ("hs" pre-scaled hidden rows)
template <int K, bool RELU, bool BIAS, bool SCALE>
__global__ __launch_bounds__(256) void k_mm_slice(const float* __restrict__ X,
                                                  const float* __restrict__ WT,   // [64][K]
                                                  const float* __restrict__ bias,
                                                  const float* __restrict__ dinv,
                                                  float* __restrict__ Y, int N) {
    int n = blockIdx.x * 256 + threadIdx.x;
    int j0 = blockIdx.y * 16;
    int nc = n < N ? n : N - 1;
    const float* xr = X + (size_t)nc * K;
    const float* wr = WT + (size_t)j0 * K;
    float acc[16];
#pragma unroll
    for (int j = 0; j < 16; ++j) acc[j] = BIAS ? bias[j0 + j] : 0.f;
#pragma unroll 1
    for (int k0 = 0; k0 < K; k0 += 8) {
        float ef[8];
        *(float4*)(ef)     = *(const float4*)(xr + k0);
        *(float4*)(ef + 4) = *(const float4*)(xr + k0 + 4);
        if (RELU) {
#pragma unroll
            for (int kk = 0; kk < 8; ++kk) ef[kk] = fmaxf(ef[kk], 0.f);
        }
#pragma unroll
        for (int j = 0; j < 16; ++j) {
#pragma unroll
            for (int kk = 0; kk < 8; ++kk)
                acc[j] = fmaf(ef[kk], wr[j * K + k0 + kk], acc[j]);
        }
    }
    if (n < N) {
        if (SCALE) {
            float dn = dinv[n];
#pragma unroll
            for (int j = 0; j < 16; ++j) acc[j] *= dn;
        }
        float4* yp = (float4*)(Y + (size_t)n * 64 + j0);
#pragma unroll
        for (int q = 0; q < 4; ++q) yp[q] = *(float4*)(acc + q * 4);
    }
}

// ---------------- fused P+Q GEMM (round-4 proven G8 form): y<4 -> P(+bm1), y>=4 -> Q ----------------
__global__ __launch_bounds__(256) void k_pq_slice(const float* __restrict__ A2,
                                                  const float* __restrict__ WPQ,  // [128][64]
                                                  const float* __restrict__ bm1,
                                                  float* __restrict__ Pb, float* __restrict__ Qb, int N) {
    int n = blockIdx.x * 256 + threadIdx.x;
    int j0g = blockIdx.y * 16;           // 0..127 row into WPQ
    bool isP = j0g < 64;
    int jo = isP ? j0g : j0g - 64;
    float* Y = isP ? Pb : Qb;
    int nc = n < N ? n : N - 1;
    const float* xr = A2 + (size_t)nc * 64;
    const float* wr = WPQ + (size_t)j0g * 64;
    float acc[16];
#pragma unroll
    for (int j = 0; j < 16; ++j) acc[j] = isP ? bm1[jo + j] : 0.f;
#pragma unroll 1
    for (int k0 = 0; k0 < 64; k0 += 8) {
        float ef[8];
        *(float4*)(ef)     = *(const float4*)(xr + k0);
        *(float4*)(ef + 4) = *(const float4*)(xr + k0 + 4);
#pragma unroll
        for (int kk = 0; kk < 8; ++kk) ef[kk] = fmaxf(ef[kk], 0.f);
#pragma unroll
        for (int j = 0; j < 16; ++j)
#pragma unroll
            for (int kk = 0; kk < 8; ++kk)
                acc[j] = fmaf(ef[kk], wr[j * 64 + k0 + kk], acc[j]);
    }
    if (n < N) {
        float4* yp = (float4*)(Y + (size_t)n * 64 + jo);
#pragma unroll
        for (int q = 0; q < 4; ++q) yp[q] = *(float4*)(acc + q * 4);
    }
}

// ---------------- segmented CSR gather: a[d] = bias + dd*(hs[d] + sum over NCH chunk-segments) ----------------
// wave = dst node, lane = column; register accumulator across segments (no extra a traffic).
template <bool PAIR>
__global__ __launch_bounds__(256) void k_gather(const float* __restrict__ hs, const float* __restrict__ dinv,
                                                const int* __restrict__ rowst, const void* __restrict__ item,
                                                const int* __restrict__ srcArr,
                                                const float* __restrict__ bias,
                                                float* __restrict__ a, int N, int NCH) {
    int w = threadIdx.x >> 6, lane = threadIdx.x & 63;
    int d = blockIdx.x * 4 + w;
    if (d >= N) return;
    float dd = dinv[d];
    float acc = hs[(size_t)d * 64 + lane];   // self-loop term (pre-scaled)
    for (int c = 0; c < NCH; ++c) {
        int f = c * N + d;
        int k = rowst[f], kend = rowst[f + 1];
        for (; k + 4 <= kend; k += 4) {
            int s0, s1, s2, s3;
            if (PAIR) {
                const int2* it = (const int2*)item;
                int2 p0 = it[k], p1 = it[k + 1], p2 = it[k + 2], p3 = it[k + 3];
                s0 = p0.x; s1 = p1.x; s2 = p2.x; s3 = p3.x;
            } else {
                const int* eid = (const int*)item;
                int e0 = eid[k], e1 = eid[k + 1], e2 = eid[k + 2], e3 = eid[k + 3];
                s0 = srcArr[e0]; s1 = srcArr[e1]; s2 = srcArr[e2]; s3 = srcArr[e3];
            }
            float v0 = hs[(size_t)s0 * 64 + lane], v1 = hs[(size_t)s1 * 64 + lane];
            float v2 = hs[(size_t)s2 * 64 + lane], v3 = hs[(size_t)s3 * 64 + lane];
            acc += v0; acc += v1; acc += v2; acc += v3;
        }
        for (; k < kend; ++k) {
            int s = PAIR ? ((const int2*)item)[k].x : srcArr[((const int*)item)[k]];
            acc += hs[(size_t)s * 64 + lane];
        }
    }
    a[(size_t)d * 64 + lane] = fmaf(acc, dd, bias[lane]);
}

// ---------------- fallback P pass (row-local, in-place over A2) ----------------
__global__ __launch_bounds__(256) void k_p_inplace(float* __restrict__ A2P,
                                                   const float* __restrict__ WPQ,
                                                   const float* __restrict__ bm1, int N) {
    int n = blockIdx.x * 256 + threadIdx.x;
    int nc = n < N ? n : N - 1;
    const float* xr = A2P + (size_t)nc * 64;
    float acc[64];
#pragma unroll
    for (int j = 0; j < 64; ++j) acc[j] = bm1[j];
#pragma unroll 1
    for (int k0 = 0; k0 < 64; k0 += 8) {
        float ef[8];
        *(float4*)(ef)     = *(const float4*)(xr + k0);
        *(float4*)(ef + 4) = *(const float4*)(xr + k0 + 4);
#pragma unroll
        for (int kk = 0; kk < 8; ++kk) ef[kk] = fmaxf(ef[kk], 0.f);
#pragma unroll
        for (int j = 0; j < 64; ++j)
#pragma unroll
            for (int kk = 0; kk < 8; ++kk)
                acc[j] = fmaf(ef[kk], WPQ[j * 64 + k0 + kk], acc[j]);
    }
    if (n < N) {
#pragma unroll
        for (int q = 0; q < 16; ++q)
            *(float4*)(A2P + (size_t)n * 64 + q * 4) = *(float4*)(acc + q * 4);
    }
}

// ---------------- edge epilogue, ORIGINAL order (tier-2 fallback) ----------------
__global__ __launch_bounds__(256) void k_edge_pq(const float* __restrict__ P,
                                                 const float* __restrict__ Q,
                                                 const int* __restrict__ src,
                                                 const int* __restrict__ dst,
                                                 const float* __restrict__ W2T,
                                                 const float* __restrict__ bm2,
                                                 float* __restrict__ out, int E) {
    int e = blockIdx.x * 256 + threadIdx.x;
    int ec = e < E ? e : E - 1;
    int s = src[ec], d = dst[ec];
    const float4* p4 = (const float4*)(P + (size_t)s * 64);
    const float4* q4 = (const float4*)(Q + (size_t)d * 64);
    float z[64];
#pragma unroll
    for (int c = 0; c < 16; ++c) {
        float4 a = p4[c], b = q4[c];
        z[c * 4 + 0] = fmaxf(a.x + b.x, 0.f);
        z[c * 4 + 1] = fmaxf(a.y + b.y, 0.f);
        z[c * 4 + 2] = fmaxf(a.z + b.z, 0.f);
        z[c * 4 + 3] = fmaxf(a.w + b.w, 0.f);
    }
    float o[16];
#pragma unroll
    for (int c = 0; c < 16; ++c) {
        float a = bm2[c];
#pragma unroll
        for (int j = 0; j < 64; ++j) a = fmaf(z[j], W2T[c * 64 + j], a);
        o[c] = a;
    }
    if (e < E) {
        float4* op = (float4*)(out + (size_t)e * 16);
#pragma unroll
        for (int q = 0; q < 4; ++q) op[q] = *(float4*)(o + q * 4);
    }
}

// ---------------- edge epilogue, (chunk,d)-CSR order, dvec-indexed, fused accumulate ----------------
// Thread = 1 CSR position. Within a chunk segment: P reads land in a 2 MB window (L2-resident);
// consecutive threads share d -> Q row L1-broadcast; out[eid] scattered (write floor unchanged).
template <bool PAIR>
__global__ __launch_bounds__(256) void k_edge_csr(const float* __restrict__ P,
                                                  const float* __restrict__ Q,
                                                  const int* __restrict__ dvec,
                                                  const void* __restrict__ item,
                                                  const int* __restrict__ srcArr,
                                                  const float* __restrict__ W2T,  // [16][64]
                                                  const float* __restrict__ bm2,
                                                  float* __restrict__ out, int E) {
    int i = blockIdx.x * 256 + threadIdx.x;
    int ic = i < E ? i : E - 1;
    int s, e;
    if (PAIR) {
        int2 pe = ((const int2*)item)[ic];
        s = pe.x; e = pe.y;
    } else {
        e = ((const int*)item)[ic];
        s = srcArr[e];
    }
    int d = dvec[ic];
    const float4* p4 = (const float4*)(P + (size_t)s * 64);
    const float4* q4 = (const float4*)(Q + (size_t)d * 64);
    float o[16];
#pragma unroll
    for (int t = 0; t < 16; ++t) o[t] = bm2[t];
#pragma unroll
    for (int cc = 0; cc < 16; ++cc) {
        float4 a = p4[cc], b = q4[cc];
        float z0 = fmaxf(a.x + b.x, 0.f);
        float z1 = fmaxf(a.y + b.y, 0.f);
        float z2 = fmaxf(a.z + b.z, 0.f);
        float z3 = fmaxf(a.w + b.w, 0.f);
#pragma unroll
        for (int t = 0; t < 16; ++t) {
            o[t] = fmaf(z0, W2T[t * 64 + cc * 4 + 0], o[t]);
            o[t] = fmaf(z1, W2T[t * 64 + cc * 4 + 1], o[t]);
            o[t] = fmaf(z2, W2T[t * 64 + cc * 4 + 2], o[t]);
            o[t] = fmaf(z3, W2T[t * 64 + cc * 4 + 3], o[t]);
        }
    }
    if (i < E) {
        float4* op = (float4*)(out + (size_t)e * 16);
#pragma unroll
        for (int q = 0; q < 4; ++q) op[q] = *(float4*)(o + q * 4);
    }
}

extern "C" void kernel_launch(void* const* d_in, const int* in_sizes, int n_in,
                              void* d_out, int out_size, void* d_ws, size_t ws_size,
                              hipStream_t stream) {
    const float* x   = (const float*)d_in[0];
    const int* ei    = (const int*)d_in[1];
    const float* W1  = (const float*)d_in[2];
    const float* b1  = (const float*)d_in[3];
    const float* W2  = (const float*)d_in[4];
    const float* b2  = (const float*)d_in[5];
    const float* Wm1 = (const float*)d_in[6];
    const float* bm1 = (const float*)d_in[7];
    const float* Wm2 = (const float*)d_in[8];
    const float* bm2 = (const float*)d_in[9];
    float* out = (float*)d_out;

    const int H  = in_sizes[3];          // 64
    const int IN = in_sizes[2] / H;      // 128
    const int N  = in_sizes[0] / IN;     // 50000
    const int E  = in_sizes[1] / 2;      // 800000
    const int* src = ei;
    const int* dst = ei + E;

    const int NCH = (N + (1 << CHS) - 1) >> CHS;   // 7 for N=50000
    const int TOT = NCH * N;                        // flattened (chunk,d) rows

    auto al = [](size_t b) { return (b + 255) & ~(size_t)255; };
    char* ws = (char*)d_ws;

    const size_t wb     = al((size_t)IN * H * 4) + al((size_t)H * H * 4) + al((size_t)2 * H * H * 4) + al((size_t)H * 16 * 4);
    const size_t rowstB = al(((size_t)TOT + 1) * 4);
    const size_t nodeB  = al((size_t)N * 64 * 4);
    const size_t pairB  = al((size_t)E * 8);
    const size_t eidB   = al((size_t)E * 4);
    const size_t needA  = wb + rowstB + pairB + 3 * nodeB;   // ~46.3 MB
    const size_t needB  = wb + rowstB + eidB  + 3 * nodeB;   // ~43.1 MB (<= 45.1 proven)

    // tier 0: int2{s,eid}; tier 1: eid-only (s via ei); tier 2: round-2 fallback
    const int tier = (needA <= ws_size) ? 0 : (needB <= ws_size) ? 1 : 2;

    float *W1T, *W2T, *WPQ, *Wm2T, *bufB, *Qbuf, *Pbuf, *dinv;
    int *degc, *rowst, *cursor, *bsum;
    void* item;
    float* bufA = (float*)d_out;   // hs buffer: dead before the epilogue writes out
    bool slicedP = true;

    size_t off = 0;
    auto alc = [&](size_t b) { void* p = ws + off; off += al(b); return p; };

    if (tier <= 1) {
        W1T  = (float*)alc((size_t)IN * H * 4);
        W2T  = (float*)alc((size_t)H * H * 4);
        WPQ  = (float*)alc((size_t)2 * H * H * 4);
        Wm2T = (float*)alc((size_t)H * 16 * 4);
        rowst = (int*)alc(((size_t)TOT + 1) * 4);
        item  = alc(tier == 0 ? (size_t)E * 8 : (size_t)E * 4);
        bufB = (float*)alc((size_t)N * 64 * 4);
        Qbuf = (float*)alc((size_t)N * 64 * 4);
        Pbuf = (float*)alc((size_t)N * 64 * 4);
        // dinv/degc/cursor/bsum alias Pbuf (4.4 MB < 12.8): all dead before the P/Q GEMM writes Pbuf
        // (dinv last read by the layer-2 GEMM SCALE, which precedes k_pq_slice)
        char* pz = (char*)Pbuf;
        size_t po = 0;
        dinv   = (float*)(pz + po); po += al((size_t)N * 4);
        degc   = (int*)(pz + po);   po += al((size_t)TOT * 4);
        cursor = (int*)(pz + po);   po += al((size_t)TOT * 4);
        bsum   = (int*)(pz + po);   po += al(8192);
    } else {
        // fallback layout: CSR lives in Qbuf (consumed before Q-GEMM writes it)
        dinv = (float*)alc((size_t)N * 4);
        W1T  = (float*)alc((size_t)IN * H * 4);
        W2T  = (float*)alc((size_t)H * H * 4);
        WPQ  = (float*)alc((size_t)2 * H * H * 4);
        Wm2T = (float*)alc((size_t)H * 16 * 4);
        bufB = (float*)alc((size_t)N * 64 * 4);
        Qbuf = (float*)alc((size_t)N * 64 * 4);
        float* PbufSep = (float*)alc((size_t)N * 64 * 4);
        slicedP = (off <= ws_size);
        Pbuf = slicedP ? PbufSep : bufB;
        char* qz = (char*)Qbuf;
        size_t qo = 0;
        degc   = (int*)(qz + qo); qo += al((size_t)TOT * 4);
        rowst  = (int*)(qz + qo); qo += al(((size_t)TOT + 1) * 4);
        cursor = (int*)(qz + qo); qo += al((size_t)TOT * 4);
        bsum   = (int*)(qz + qo); qo += al(8192);
        item   = (void*)(qz + qo);                      // eid-only, 3.2 MB, fits (total ~7.5 < 12.8)
    }

    const int NBn = (N + 255) / 256;     // 196
    const int NBe = (E + 255) / 256;     // 3125
    const int NBt = (TOT + 255) / 256;   // 1368 for N=50000
    const int NG  = (N + 3) / 4;

    // ---- chunked degree + dinv + (chunk,d)-CSR build ----
    hipMemsetAsync(degc, 0, (size_t)TOT * sizeof(int), stream);
    k_deg<<<NBe, 256, 0, stream>>>(src, dst, degc, E, N);
    k_dinv<<<NBn, 256, 0, stream>>>(degc, dinv, N, NCH);
    k_scan_sum<<<NBt, 256, 0, stream>>>(degc, bsum, TOT);
    k_scan_off<<<1, 256, 0, stream>>>(bsum, NBt);
    k_scan_write<<<NBt, 256, 0, stream>>>(degc, bsum, rowst, cursor, TOT);
    if (tier == 0) k_fill<true ><<<NBe, 256, 0, stream>>>(src, dst, cursor, item, E, N);
    else           k_fill<false><<<NBe, 256, 0, stream>>>(src, dst, cursor, item, E, N);

    // ---- merged weight prep ----
    const int prepElems = IN * H + H * H + H * 16 + 2 * H * H;
    k_prep<<<(prepElems + 255) / 256, 256, 0, stream>>>(W1, W2, Wm2, Wm1, W1T, W2T, Wm2T, WPQ, IN, H);

    const dim3 G4(NBn, 4);
    const dim3 G8(NBn, 8);

    // layer 1: hs1 = (x@W1)*dinv -> bufA ; a1 = b1 + dd*(hs1[d] + sum hs1[s]) -> bufB
    k_mm_slice<128, false, false, true><<<G4, 256, 0, stream>>>(x, W1T, nullptr, dinv, bufA, N);
    if (tier == 0) k_gather<true ><<<NG, 256, 0, stream>>>(bufA, dinv, rowst, item, src, b1, bufB, N, NCH);
    else           k_gather<false><<<NG, 256, 0, stream>>>(bufA, dinv, rowst, item, src, b1, bufB, N, NCH);

    // layer 2: hs2 = (relu(a1)@W2)*dinv -> bufA ; a2 -> bufB
    k_mm_slice<64, true, false, true><<<G4, 256, 0, stream>>>(bufB, W2T, nullptr, dinv, bufA, N);
    if (tier == 0) k_gather<true ><<<NG, 256, 0, stream>>>(bufA, dinv, rowst, item, src, b2, bufB, N, NCH);
    else           k_gather<false><<<NG, 256, 0, stream>>>(bufA, dinv, rowst, item, src, b2, bufB, N, NCH);

    // node-side MLP halves
    if (tier <= 1) {
        // fused P+Q dispatch (round-4 proven G8 form); dinv dead from here
        k_pq_slice<<<G8, 256, 0, stream>>>(bufB, WPQ, bm1, Pbuf, Qbuf, N);
        // dvec into bufB (a2 dead after k_pq_slice)
        int* dvec = (int*)bufB;
        k_dvec<<<NBt, 256, 0, stream>>>(rowst, dvec, N, TOT);
        if (tier == 0) k_edge_csr<true ><<<NBe, 256, 0, stream>>>(Pbuf, Qbuf, dvec, item, src, Wm2T, bm2, out, E);
        else           k_edge_csr<false><<<NBe, 256, 0, stream>>>(Pbuf, Qbuf, dvec, item, src, Wm2T, bm2, out, E);
    } else {
        k_mm_slice<64, true, false, false><<<G4, 256, 0, stream>>>(bufB, WPQ + 64 * 64, nullptr, nullptr, Qbuf, N);
        if (slicedP) k_mm_slice<64, true, true, false><<<G4, 256, 0, stream>>>(bufB, WPQ, bm1, nullptr, Pbuf, N);
        else         k_p_inplace<<<NBn, 256, 0, stream>>>(bufB, WPQ, bm1, N);
        k_edge_pq<<<NBe, 256, 0, stream>>>(Pbuf, Qbuf, src, dst, Wm2T, bm2, out, E);
    }
}

// Round 11
// 407.616 us; speedup vs baseline: 1.2159x; 1.2159x over previous
//
#include <hip/hip_runtime.h>
#include <hip/hip_bf16.h>

// ---------------- degree ----------------
__global__ __launch_bounds__(256) void k_deg(const int* __restrict__ dst, int* __restrict__ deg, int E) {
    int e = blockIdx.x * 256 + threadIdx.x;
    if (e < E) atomicAdd(&deg[dst[e]], 1);
}

// ---------------- CSR build: scan_sum (+fused dinv) + scan_off + scan_write + fill ----------------
__global__ __launch_bounds__(256) void k_scan_sum(const int* __restrict__ deg, int* __restrict__ bsum,
                                                  float* __restrict__ dinv, int N) {
    int n = blockIdx.x * 256 + threadIdx.x;
    int v = (n < N) ? deg[n] : 0;
    if (n < N) dinv[n] = rsqrtf((float)(v + 1));   // fused: dinv = rsqrt(deg+1) (self-loop)
    int r = v;
#pragma unroll
    for (int o = 32; o > 0; o >>= 1) r += __shfl_down(r, o, 64);
    __shared__ int sh[4];
    if ((threadIdx.x & 63) == 0) sh[threadIdx.x >> 6] = r;
    __syncthreads();
    if (threadIdx.x == 0) bsum[blockIdx.x] = sh[0] + sh[1] + sh[2] + sh[3];
}

__global__ __launch_bounds__(256) void k_scan_off(int* __restrict__ bsum, int nb) {
    __shared__ int sh[256];
    int t = threadIdx.x;
    sh[t] = (t < nb) ? bsum[t] : 0;
    __syncthreads();
    for (int o = 1; o < 256; o <<= 1) {
        int y = (t >= o) ? sh[t - o] : 0;
        __syncthreads();
        sh[t] += y;
        __syncthreads();
    }
    if (t < nb) bsum[t] = (t == 0) ? 0 : sh[t - 1];
}

__global__ __launch_bounds__(256) void k_scan_write(const int* __restrict__ deg, const int* __restrict__ boff,
                                                    int* __restrict__ row_start, int* __restrict__ cursor, int N) {
    int n = blockIdx.x * 256 + threadIdx.x;
    int t = threadIdx.x, lane = t & 63, w = t >> 6;
    int v = (n < N) ? deg[n] : 0;
    int x = v;
#pragma unroll
    for (int o = 1; o < 64; o <<= 1) {
        int y = __shfl_up(x, o, 64);
        if (lane >= o) x += y;
    }
    __shared__ int wsum[4];
    if (lane == 63) wsum[w] = x;
    __syncthreads();
    int wo = 0;
#pragma unroll
    for (int i = 0; i < 4; ++i) wo += (i < w) ? wsum[i] : 0;
    int excl = boff[blockIdx.x] + wo + x - v;
    if (n < N) { row_start[n] = excl; cursor[n] = excl; }
    if (n == N - 1) row_start[N] = excl + v;
}

// PAIR: item[pos] = {src[e], e} (int2) ; else item[pos] = e (int)
template <bool PAIR>
__global__ __launch_bounds__(256) void k_fill(const int* __restrict__ src, const int* __restrict__ dst,
                                              int* __restrict__ cursor, void* __restrict__ item, int E) {
    int e = blockIdx.x * 256 + threadIdx.x;
    if (e < E) {
        int d = dst[e];
        int pos = atomicAdd(&cursor[d], 1);
        if (PAIR) ((int2*)item)[pos] = make_int2(src[e], e);
        else      ((int*)item)[pos] = e;
    }
}

// ---------------- dvec[i] = d for CSR position i ----------------
__global__ __launch_bounds__(256) void k_dvec(const int* __restrict__ rowst, int* __restrict__ dvec, int N) {
    int w = threadIdx.x >> 6, lane = threadIdx.x & 63;
    int d = blockIdx.x * 4 + w;
    if (d >= N) return;
    int beg = rowst[d], end = rowst[d + 1];
    for (int k = beg + lane; k < end; k += 64) dvec[k] = d;
}

// ---------------- merged weight prep: W1T, W2T, Wm2T, WPQ in one dispatch ----------------
__global__ __launch_bounds__(256) void k_prep(const float* __restrict__ W1, const float* __restrict__ W2,
                                              const float* __restrict__ Wm2, const float* __restrict__ Wm1,
                                              float* __restrict__ W1T, float* __restrict__ W2T,
                                              float* __restrict__ Wm2T, float* __restrict__ WPQ,
                                              int IN, int H) {
    int i = blockIdx.x * 256 + threadIdx.x;
    int n1 = IN * H, n2 = H * H, n3 = H * 16, n4 = 2 * H * H;
    if (i < n1) {
        int r = i / H, c = i % H;
        W1T[(size_t)c * IN + r] = W1[(size_t)r * H + c];
    } else if ((i -= n1) < n2) {
        int r = i / H, c = i % H;
        W2T[(size_t)c * H + r] = W2[(size_t)r * H + c];
    } else if ((i -= n2) < n3) {
        int r = i / 16, c = i % 16;
        Wm2T[(size_t)c * H + r] = Wm2[(size_t)r * 16 + c];
    } else if ((i -= n3) < n4) {
        int j = i >> 6, k = i & 63;   // H == 64
        WPQ[i] = (j < 64) ? Wm1[k * 64 + j] : Wm1[(64 + k) * 64 + (j - 64)];
    }
}

// ---------------- column-sliced node GEMM (HW-proven round 2) ----------------
// SCALE: write acc*dinv[n]  ("hs" pre-scaled hidden rows)
template <int K, bool RELU, bool BIAS, bool SCALE>
__global__ __launch_bounds__(256) void k_mm_slice(const float* __restrict__ X,
                                                  const float* __restrict__ WT,   // [64][K]
                                                  const float* __restrict__ bias,
                                                  const float* __restrict__ dinv,
                                                  float* __restrict__ Y, int N) {
    int n = blockIdx.x * 256 + threadIdx.x;
    int j0 = blockIdx.y * 16;
    int nc = n < N ? n : N - 1;
    const float* xr = X + (size_t)nc * K;
    const float* wr = WT + (size_t)j0 * K;
    float acc[16];
#pragma unroll
    for (int j = 0; j < 16; ++j) acc[j] = BIAS ? bias[j0 + j] : 0.f;
#pragma unroll 1
    for (int k0 = 0; k0 < K; k0 += 8) {
        float ef[8];
        *(float4*)(ef)     = *(const float4*)(xr + k0);
        *(float4*)(ef + 4) = *(const float4*)(xr + k0 + 4);
        if (RELU) {
#pragma unroll
            for (int kk = 0; kk < 8; ++kk) ef[kk] = fmaxf(ef[kk], 0.f);
        }
#pragma unroll
        for (int j = 0; j < 16; ++j) {
#pragma unroll
            for (int kk = 0; kk < 8; ++kk)
                acc[j] = fmaf(ef[kk], wr[j * K + k0 + kk], acc[j]);
        }
    }
    if (n < N) {
        if (SCALE) {
            float dn = dinv[n];
#pragma unroll
            for (int j = 0; j < 16; ++j) acc[j] *= dn;
        }
        float4* yp = (float4*)(Y + (size_t)n * 64 + j0);
#pragma unroll
        for (int q = 0; q < 4; ++q) yp[q] = *(float4*)(acc + q * 4);
    }
}

// ---------------- fused P+Q GEMM (round-4 proven G8 form): y<4 -> P(+bm1), y>=4 -> Q ----------------
__global__ __launch_bounds__(256) void k_pq_slice(const float* __restrict__ A2,
                                                  const float* __restrict__ WPQ,  // [128][64]
                                                  const float* __restrict__ bm1,
                                                  float* __restrict__ Pb, float* __restrict__ Qb, int N) {
    int n = blockIdx.x * 256 + threadIdx.x;
    int j0g = blockIdx.y * 16;           // 0..127 row into WPQ
    bool isP = j0g < 64;
    int jo = isP ? j0g : j0g - 64;
    float* Y = isP ? Pb : Qb;
    int nc = n < N ? n : N - 1;
    const float* xr = A2 + (size_t)nc * 64;
    const float* wr = WPQ + (size_t)j0g * 64;
    float acc[16];
#pragma unroll
    for (int j = 0; j < 16; ++j) acc[j] = isP ? bm1[jo + j] : 0.f;
#pragma unroll 1
    for (int k0 = 0; k0 < 64; k0 += 8) {
        float ef[8];
        *(float4*)(ef)     = *(const float4*)(xr + k0);
        *(float4*)(ef + 4) = *(const float4*)(xr + k0 + 4);
#pragma unroll
        for (int kk = 0; kk < 8; ++kk) ef[kk] = fmaxf(ef[kk], 0.f);
#pragma unroll
        for (int j = 0; j < 16; ++j)
#pragma unroll
            for (int kk = 0; kk < 8; ++kk)
                acc[j] = fmaf(ef[kk], wr[j * 64 + k0 + kk], acc[j]);
    }
    if (n < N) {
        float4* yp = (float4*)(Y + (size_t)n * 64 + jo);
#pragma unroll
        for (int q = 0; q < 4; ++q) yp[q] = *(float4*)(acc + q * 4);
    }
}

// ---------------- CSR gather over pre-scaled rows: a[d] = bias + dd*(hs[d] + sum_e hs[src_e]) ----------------
// wave = dst node, lane = column. 16-row, then 8-row batches in flight.
template <bool PAIR>
__global__ __launch_bounds__(256) void k_gather(const float* __restrict__ hs, const float* __restrict__ dinv,
                                                const int* __restrict__ row_start, const void* __restrict__ item,
                                                const int* __restrict__ srcArr,
                                                const float* __restrict__ bias,
                                                float* __restrict__ a, int N) {
    int w = threadIdx.x >> 6, lane = threadIdx.x & 63;
    int d = blockIdx.x * 4 + w;
    if (d >= N) return;
    int beg = row_start[d], end = row_start[d + 1];
    float dd = dinv[d];
    float acc = hs[(size_t)d * 64 + lane];   // self-loop term (pre-scaled)
    int k = beg;
    for (; k + 16 <= end; k += 16) {
        int ss[16];
        if (PAIR) {
            const int2* it = (const int2*)item;
#pragma unroll
            for (int u = 0; u < 16; ++u) ss[u] = it[k + u].x;
        } else {
            const int* eid = (const int*)item;
            int ee[16];
#pragma unroll
            for (int u = 0; u < 16; ++u) ee[u] = eid[k + u];
#pragma unroll
            for (int u = 0; u < 16; ++u) ss[u] = srcArr[ee[u]];
        }
        float v[16];
#pragma unroll
        for (int u = 0; u < 16; ++u) v[u] = hs[(size_t)ss[u] * 64 + lane];
#pragma unroll
        for (int u = 0; u < 16; ++u) acc += v[u];
    }
    for (; k + 8 <= end; k += 8) {
        int ss[8];
        if (PAIR) {
            const int2* it = (const int2*)item;
#pragma unroll
            for (int u = 0; u < 8; ++u) ss[u] = it[k + u].x;
        } else {
            const int* eid = (const int*)item;
            int ee[8];
#pragma unroll
            for (int u = 0; u < 8; ++u) ee[u] = eid[k + u];
#pragma unroll
            for (int u = 0; u < 8; ++u) ss[u] = srcArr[ee[u]];
        }
        float v[8];
#pragma unroll
        for (int u = 0; u < 8; ++u) v[u] = hs[(size_t)ss[u] * 64 + lane];
#pragma unroll
        for (int u = 0; u < 8; ++u) acc += v[u];
    }
    for (; k < end; ++k) {
        int s = PAIR ? ((const int2*)item)[k].x : srcArr[((const int*)item)[k]];
        acc += hs[(size_t)s * 64 + lane];
    }
    a[(size_t)d * 64 + lane] = fmaf(acc, dd, bias[lane]);
}

// ---------------- fallback P pass (row-local, in-place over A2) ----------------
__global__ __launch_bounds__(256) void k_p_inplace(float* __restrict__ A2P,
                                                   const float* __restrict__ WPQ,
                                                   const float* __restrict__ bm1, int N) {
    int n = blockIdx.x * 256 + threadIdx.x;
    int nc = n < N ? n : N - 1;
    const float* xr = A2P + (size_t)nc * 64;
    float acc[64];
#pragma unroll
    for (int j = 0; j < 64; ++j) acc[j] = bm1[j];
#pragma unroll 1
    for (int k0 = 0; k0 < 64; k0 += 8) {
        float ef[8];
        *(float4*)(ef)     = *(const float4*)(xr + k0);
        *(float4*)(ef + 4) = *(const float4*)(xr + k0 + 4);
#pragma unroll
        for (int kk = 0; kk < 8; ++kk) ef[kk] = fmaxf(ef[kk], 0.f);
#pragma unroll
        for (int j = 0; j < 64; ++j)
#pragma unroll
            for (int kk = 0; kk < 8; ++kk)
                acc[j] = fmaf(ef[kk], WPQ[j * 64 + k0 + kk], acc[j]);
    }
    if (n < N) {
#pragma unroll
        for (int q = 0; q < 16; ++q)
            *(float4*)(A2P + (size_t)n * 64 + q * 4) = *(float4*)(acc + q * 4);
    }
}

// ---------------- edge epilogue, ORIGINAL order (tier-2 fallback) ----------------
__global__ __launch_bounds__(256) void k_edge_pq(const float* __restrict__ P,
                                                 const float* __restrict__ Q,
                                                 const int* __restrict__ src,
                                                 const int* __restrict__ dst,
                                                 const float* __restrict__ W2T,
                                                 const float* __restrict__ bm2,
                                                 float* __restrict__ out, int E) {
    int e = blockIdx.x * 256 + threadIdx.x;
    int ec = e < E ? e : E - 1;
    int s = src[ec], d = dst[ec];
    const float4* p4 = (const float4*)(P + (size_t)s * 64);
    const float4* q4 = (const float4*)(Q + (size_t)d * 64);
    float z[64];
#pragma unroll
    for (int c = 0; c < 16; ++c) {
        float4 a = p4[c], b = q4[c];
        z[c * 4 + 0] = fmaxf(a.x + b.x, 0.f);
        z[c * 4 + 1] = fmaxf(a.y + b.y, 0.f);
        z[c * 4 + 2] = fmaxf(a.z + b.z, 0.f);
        z[c * 4 + 3] = fmaxf(a.w + b.w, 0.f);
    }
    float o[16];
#pragma unroll
    for (int c = 0; c < 16; ++c) {
        float a = bm2[c];
#pragma unroll
        for (int j = 0; j < 64; ++j) a = fmaf(z[j], W2T[c * 64 + j], a);
        o[c] = a;
    }
    if (e < E) {
        float4* op = (float4*)(out + (size_t)e * 16);
#pragma unroll
        for (int q = 0; q < 4; ++q) op[q] = *(float4*)(o + q * 4);
    }
}

// ---------------- edge epilogue, CSR order, dvec-indexed, fused accumulate (HW-proven, 77 us) ----------------
// Thread = 1 CSR position. Consecutive threads share d -> Q row L1/L2-broadcast.
template <bool PAIR>
__global__ __launch_bounds__(256) void k_edge_csr(const float* __restrict__ P,
                                                  const float* __restrict__ Q,
                                                  const int* __restrict__ dvec,
                                                  const void* __restrict__ item,
                                                  const int* __restrict__ srcArr,
                                                  const float* __restrict__ W2T,  // [16][64]
                                                  const float* __restrict__ bm2,
                                                  float* __restrict__ out, int E) {
    int i = blockIdx.x * 256 + threadIdx.x;
    int ic = i < E ? i : E - 1;
    int s, e;
    if (PAIR) {
        int2 pe = ((const int2*)item)[ic];
        s = pe.x; e = pe.y;
    } else {
        e = ((const int*)item)[ic];
        s = srcArr[e];
    }
    int d = dvec[ic];
    const float4* p4 = (const float4*)(P + (size_t)s * 64);
    const float4* q4 = (const float4*)(Q + (size_t)d * 64);
    float o[16];
#pragma unroll
    for (int t = 0; t < 16; ++t) o[t] = bm2[t];
#pragma unroll
    for (int cc = 0; cc < 16; ++cc) {
        float4 a = p4[cc], b = q4[cc];
        float z0 = fmaxf(a.x + b.x, 0.f);
        float z1 = fmaxf(a.y + b.y, 0.f);
        float z2 = fmaxf(a.z + b.z, 0.f);
        float z3 = fmaxf(a.w + b.w, 0.f);
#pragma unroll
        for (int t = 0; t < 16; ++t) {
            o[t] = fmaf(z0, W2T[t * 64 + cc * 4 + 0], o[t]);
            o[t] = fmaf(z1, W2T[t * 64 + cc * 4 + 1], o[t]);
            o[t] = fmaf(z2, W2T[t * 64 + cc * 4 + 2], o[t]);
            o[t] = fmaf(z3, W2T[t * 64 + cc * 4 + 3], o[t]);
        }
    }
    if (i < E) {
        float4* op = (float4*)(out + (size_t)e * 16);
#pragma unroll
        for (int q = 0; q < 4; ++q) op[q] = *(float4*)(o + q * 4);
    }
}

extern "C" void kernel_launch(void* const* d_in, const int* in_sizes, int n_in,
                              void* d_out, int out_size, void* d_ws, size_t ws_size,
                              hipStream_t stream) {
    const float* x   = (const float*)d_in[0];
    const int* ei    = (const int*)d_in[1];
    const float* W1  = (const float*)d_in[2];
    const float* b1  = (const float*)d_in[3];
    const float* W2  = (const float*)d_in[4];
    const float* b2  = (const float*)d_in[5];
    const float* Wm1 = (const float*)d_in[6];
    const float* bm1 = (const float*)d_in[7];
    const float* Wm2 = (const float*)d_in[8];
    const float* bm2 = (const float*)d_in[9];
    float* out = (float*)d_out;

    const int H  = in_sizes[3];          // 64
    const int IN = in_sizes[2] / H;      // 128
    const int N  = in_sizes[0] / IN;     // 50000
    const int E  = in_sizes[1] / 2;      // 800000
    const int* src = ei;
    const int* dst = ei + E;

    auto al = [](size_t b) { return (b + 255) & ~(size_t)255; };
    char* ws = (char*)d_ws;

    const size_t wb     = al((size_t)IN * H * 4) + al((size_t)H * H * 4) + al((size_t)2 * H * H * 4) + al((size_t)H * 16 * 4);
    const size_t rowstB = al(((size_t)N + 1) * 4);
    const size_t nodeB  = al((size_t)N * 64 * 4);
    const size_t pairB  = al((size_t)E * 8);
    const size_t eidB   = al((size_t)E * 4);
    const size_t needA  = wb + rowstB + pairB + 3 * nodeB;   // ~45.1 MB
    const size_t needB  = wb + rowstB + eidB  + 3 * nodeB;   // ~41.9 MB

    // tier 0: int2{src,eid} CSR epilogue; tier 1: eid-only (src via ei); tier 2: round-2 fallback
    const int tier = (needA <= ws_size) ? 0 : (needB <= ws_size) ? 1 : 2;

    float *W1T, *W2T, *WPQ, *Wm2T, *bufB, *Qbuf, *Pbuf, *dinv;
    int *deg, *rowst, *cursor, *bsum;
    void* item;
    float* bufA = (float*)d_out;   // hs buffer: dead before the epilogue writes out
    bool slicedP = true;

    size_t off = 0;
    auto alc = [&](size_t b) { void* p = ws + off; off += al(b); return p; };

    if (tier <= 1) {
        W1T  = (float*)alc((size_t)IN * H * 4);
        W2T  = (float*)alc((size_t)H * H * 4);
        WPQ  = (float*)alc((size_t)2 * H * H * 4);
        Wm2T = (float*)alc((size_t)H * 16 * 4);
        rowst = (int*)alc(((size_t)N + 1) * 4);
        item  = alc(tier == 0 ? (size_t)E * 8 : (size_t)E * 4);
        bufB = (float*)alc((size_t)N * 64 * 4);
        Qbuf = (float*)alc((size_t)N * 64 * 4);
        Pbuf = (float*)alc((size_t)N * 64 * 4);
        // deg/dinv/cursor/bsum alias Pbuf: all dead before the P/Q GEMM writes Pbuf
        // (dinv last used by the layer-2 GEMM SCALE, which precedes k_pq_slice)
        char* pz = (char*)Pbuf;
        dinv   = (float*)pz;
        deg    = (int*)(pz + al((size_t)N * 4));
        cursor = (int*)(pz + 2 * al((size_t)N * 4));
        bsum   = (int*)(pz + 3 * al((size_t)N * 4));
    } else {
        // round-2 proven layout: CSR lives in Qbuf (consumed before Q-GEMM writes it)
        dinv = (float*)alc((size_t)N * 4);
        W1T  = (float*)alc((size_t)IN * H * 4);
        W2T  = (float*)alc((size_t)H * H * 4);
        WPQ  = (float*)alc((size_t)2 * H * H * 4);
        Wm2T = (float*)alc((size_t)H * 16 * 4);
        bufB = (float*)alc((size_t)N * 64 * 4);
        Qbuf = (float*)alc((size_t)N * 64 * 4);
        float* PbufSep = (float*)alc((size_t)N * 64 * 4);
        slicedP = (off <= ws_size);
        Pbuf = slicedP ? PbufSep : bufB;
        char* qz = (char*)Qbuf;
        size_t qo = 0;
        deg    = (int*)(qz + qo); qo += al((size_t)N * 4);
        rowst  = (int*)(qz + qo); qo += al(((size_t)N + 1) * 4);
        cursor = (int*)(qz + qo); qo += al((size_t)N * 4);
        bsum   = (int*)(qz + qo); qo += al(1024);
        item   = (void*)(qz + qo);                      // int2 pairs, ~6.4 MB, fits in 12.8
    }

    const int NBn = (N + 255) / 256;   // 196 (<=256 required by k_scan_off)
    const int NBe = (E + 255) / 256;
    const int NG  = (N + 3) / 4;

    // ---- degree + dinv + CSR build ----
    hipMemsetAsync(deg, 0, (size_t)N * sizeof(int), stream);
    k_deg<<<NBe, 256, 0, stream>>>(dst, deg, E);
    k_scan_sum<<<NBn, 256, 0, stream>>>(deg, bsum, dinv, N);
    k_scan_off<<<1, 256, 0, stream>>>(bsum, NBn);
    k_scan_write<<<NBn, 256, 0, stream>>>(deg, bsum, rowst, cursor, N);
    if (tier == 1) k_fill<false><<<NBe, 256, 0, stream>>>(src, dst, cursor, item, E);
    else           k_fill<true ><<<NBe, 256, 0, stream>>>(src, dst, cursor, item, E);

    // ---- merged weight prep ----
    const int prepElems = IN * H + H * H + H * 16 + 2 * H * H;
    k_prep<<<(prepElems + 255) / 256, 256, 0, stream>>>(W1, W2, Wm2, Wm1, W1T, W2T, Wm2T, WPQ, IN, H);

    const dim3 G4(NBn, 4);
    const dim3 G8(NBn, 8);

    // layer 1: hs1 = (x@W1)*dinv -> bufA ; a1 = b1 + dd*(hs1[d] + sum hs1[s]) -> bufB
    k_mm_slice<128, false, false, true><<<G4, 256, 0, stream>>>(x, W1T, nullptr, dinv, bufA, N);
    if (tier == 1) k_gather<false><<<NG, 256, 0, stream>>>(bufA, dinv, rowst, item, src, b1, bufB, N);
    else           k_gather<true ><<<NG, 256, 0, stream>>>(bufA, dinv, rowst, item, src, b1, bufB, N);

    // layer 2: hs2 = (relu(a1)@W2)*dinv -> bufA ; a2 -> bufB
    k_mm_slice<64, true, false, true><<<G4, 256, 0, stream>>>(bufB, W2T, nullptr, dinv, bufA, N);
    if (tier == 1) k_gather<false><<<NG, 256, 0, stream>>>(bufA, dinv, rowst, item, src, b2, bufB, N);
    else           k_gather<true ><<<NG, 256, 0, stream>>>(bufA, dinv, rowst, item, src, b2, bufB, N);

    // node-side MLP halves
    if (tier <= 1) {
        // fused P+Q dispatch (round-4 proven G8 form); dinv dead from here
        k_pq_slice<<<G8, 256, 0, stream>>>(bufB, WPQ, bm1, Pbuf, Qbuf, N);
        // dvec into bufB (a2 dead after k_pq_slice)
        int* dvec = (int*)bufB;
        k_dvec<<<NG, 256, 0, stream>>>(rowst, dvec, N);
        if (tier == 0) k_edge_csr<true ><<<NBe, 256, 0, stream>>>(Pbuf, Qbuf, dvec, item, src, Wm2T, bm2, out, E);
        else           k_edge_csr<false><<<NBe, 256, 0, stream>>>(Pbuf, Qbuf, dvec, item, src, Wm2T, bm2, out, E);
    } else {
        k_mm_slice<64, true, false, false><<<G4, 256, 0, stream>>>(bufB, WPQ + 64 * 64, nullptr, nullptr, Qbuf, N);
        if (slicedP) k_mm_slice<64, true, true, false><<<G4, 256, 0, stream>>>(bufB, WPQ, bm1, nullptr, Pbuf, N);
        else         k_p_inplace<<<NBn, 256, 0, stream>>>(bufB, WPQ, bm1, N);
        k_edge_pq<<<NBe, 256, 0, stream>>>(Pbuf, Qbuf, src, dst, Wm2T, bm2, out, E);
    }
}